// Round 9
// baseline (334.206 us; speedup 1.0000x reference)
//
#include <hip/hip_runtime.h>
#include <math.h>

// Problem constants (fixed by reference setup_inputs)
constexpr int Nn = 2, Hh = 8, Ll = 2048, Dd = 64;
constexpr int S  = Nn * Hh;      // 16 sequences -> 16 blocks
constexpr int C  = 64;           // chunk length
constexpr int NC = Ll / C;       // 32 chunks/seq, walked serially per block

constexpr int SB  = 72;          // bf16 LDS row stride (144 B rows, 16B-aligned)
constexpr int SRP = 65;          // fp32 score-matrix stride
constexpr int SM  = 68;          // fp32 KV-master stride (float4-aligned, low-conflict)
constexpr int SSC = 17;          // fp32 scratch stride (conflict-free column reduce)

#define EPSF 1e-6f

typedef __attribute__((ext_vector_type(8))) short short8;
typedef __attribute__((ext_vector_type(4))) float f32x4;
#define MFMA16(a, b, c) __builtin_amdgcn_mfma_f32_16x16x32_bf16(a, b, c, 0, 0, 0)

__device__ __forceinline__ float sigf(float x) { return 1.0f / (1.0f + __expf(-x)); }

__device__ __forceinline__ int gidx(int n, int l, int h, int d) {
    return ((n * Ll + l) * Hh + h) * Dd + d;
}

__device__ __forceinline__ float fc(const float4& v, int u) { return ((const float*)&v)[u]; }

__device__ __forceinline__ unsigned short f2bf(float x) {
    unsigned int u = __float_as_uint(x);
    unsigned int r = (u + 0x7fffu + ((u >> 16) & 1u)) >> 16;   // RNE
    return (unsigned short)r;
}
__device__ __forceinline__ unsigned int pack2(float lo, float hi) {
    return (unsigned int)f2bf(lo) | ((unsigned int)f2bf(hi) << 16);
}
__device__ __forceinline__ float bf2f(unsigned short u) {
    return __uint_as_float(((unsigned int)u) << 16);
}

// One block per (n,h) sequence; walks 32 chunks serially with all scan state in LDS.
// 16 waves: 4x4 grid of 16x16 MFMA tiles covers every 64x64 matmul in one shot.
__global__ __launch_bounds__(1024, 1) void k_mega(const float* __restrict__ Q,
                                                  const float* __restrict__ K,
                                                  const float* __restrict__ V,
                                                  float* __restrict__ Out) {
    __shared__ __align__(16) unsigned short sqB[C * SB];  // sigmoid(q) [i][d]
    __shared__ __align__(16) unsigned short skB[C * SB];  // sigmoid(k) [i][d]; becomes stB in H
    __shared__ __align__(16) unsigned short skT[C * SB];  // sigmoid(k) [d][i]; scomp-scaled in H
    __shared__ __align__(16) unsigned short vT [C * SB];  // v [m][i] raw
    __shared__ __align__(16) unsigned short kvB[C * SB];  // bf16 exclusive KV^T [m][d]
    __shared__ __align__(16) float P[C * SRP];            // fp32 scores
    __shared__ __align__(16) float master[C * SM];        // fp32 KV^T prefix state [m][d]
    __shared__ float scrA[C * SSC], scrB[C * SSC];
    __shared__ float colK[C], colQ[C];
    __shared__ float pk[Dd], pq[Dd], pks[Dd], pqs[Dd];    // cross-chunk prefix state
    __shared__ float SKc[Dd], SQc[Dd], SKso[Dd], SQsi[Dd];
    __shared__ float lsi[C], lso[C], rw1a[C], rw2a[C], le[C], lsc[C], s2l[C];
    __shared__ float Tcum;

    const int s = blockIdx.x, n = s / Hh, h = s % Hh, t = threadIdx.x;
    const int w = t >> 6, lane = t & 63, mf = lane & 15, qq = lane >> 4;
    const int I0 = (w >> 2) * 16, J0 = (w & 3) * 16;      // wave tile position
    const int iA = t >> 4, gA = t & 15, dA = gA * 4;      // natural-staging coords

    for (int u = t; u < C * SM; u += 1024) master[u] = 0.f;
    if (t < 64) { pk[t] = 0.f; pq[t] = 0.f; pks[t] = 0.f; pqs[t] = 0.f; }
    if (t == 0) Tcum = 0.f;
    __syncthreads();

    for (int c = 0; c < NC; c++) {
        // ---- A: stage chunk (sigmoids once) ----
        {
            int id = gidx(n, c * C + iA, h, dA);
            float4 q4 = *(const float4*)&Q[id];
            float4 k4 = *(const float4*)&K[id];
            float a0 = sigf(q4.x), a1 = sigf(q4.y), a2 = sigf(q4.z), a3 = sigf(q4.w);
            float b0 = sigf(k4.x), b1 = sigf(k4.y), b2 = sigf(k4.z), b3 = sigf(k4.w);
            *(uint2*)&sqB[iA * SB + dA] = make_uint2(pack2(a0, a1), pack2(a2, a3));
            *(uint2*)&skB[iA * SB + dA] = make_uint2(pack2(b0, b1), pack2(b2, b3));
            scrA[iA * SSC + gA] = b0 + b1 + b2 + b3;   // row-sum partials (colK)
            scrB[iA * SSC + gA] = a0 + a1 + a2 + a3;   // (colQ)
        }
        if (t < 256) {   // transposed staging of K (sigmoid) and V (raw)
            int i0 = (t & 15) * 4, d0 = (t >> 4) * 4;
            float4 kr[4], vr[4];
#pragma unroll
            for (int r = 0; r < 4; r++) {
                int id = gidx(n, c * C + i0 + r, h, d0);
                kr[r] = *(const float4*)&K[id];
                vr[r] = *(const float4*)&V[id];
            }
#pragma unroll
            for (int u = 0; u < 4; u++) {
                *(uint2*)&skT[(d0 + u) * SB + i0] = make_uint2(
                    pack2(sigf(fc(kr[0], u)), sigf(fc(kr[1], u))),
                    pack2(sigf(fc(kr[2], u)), sigf(fc(kr[3], u))));
                *(uint2*)&vT[(d0 + u) * SB + i0] = make_uint2(
                    pack2(fc(vr[0], u), fc(vr[1], u)),
                    pack2(fc(vr[2], u), fc(vr[3], u)));
            }
        }
        __syncthreads();

        // ---- B (waves 0-3): reductions  +  C (all waves): P = sq·sk^T MFMA ----
        if (t < 64) {
            float v = 0.f;
#pragma unroll
            for (int u = 0; u < 16; u++) v += scrA[t * SSC + u];
            colK[t] = v;
        } else if (t < 128) {
            int i = t - 64; float v = 0.f;
#pragma unroll
            for (int u = 0; u < 16; u++) v += scrB[i * SSC + u];
            colQ[i] = v;
        } else if (t < 192) {
            int d = t - 128; float v = 0.f;
#pragma unroll
            for (int j = 0; j < 8; j++) {
                short8 x = *(const short8*)&skT[d * SB + 8 * j];
#pragma unroll
                for (int u = 0; u < 8; u++) v += bf2f((unsigned short)x[u]);
            }
            SKc[d] = v;     // column sums of sk (chunk contribution to pk)
        } else if (t < 256) {
            int d = t - 192; float v = 0.f;
            for (int i = 0; i < C; i++) v += bf2f(sqB[i * SB + d]);
            SQc[d] = v;
        }
        {
            f32x4 acc = {0, 0, 0, 0};
#pragma unroll
            for (int kk = 0; kk < 64; kk += 32) {
                short8 a = *(const short8*)&sqB[(I0 + mf) * SB + kk + qq * 8];
                short8 b = *(const short8*)&skB[(J0 + mf) * SB + kk + qq * 8];
                acc = MFMA16(a, b, acc);
            }
#pragma unroll
            for (int r = 0; r < 4; r++) P[(I0 + 4 * qq + r) * SRP + J0 + mf] = acc[r];
        }
        __syncthreads();

        // ---- D: si/so (16 threads per row) ----
        {
            int i = t >> 4, g = t & 15;
            float r1 = 0.f, r2 = 0.f;
#pragma unroll
            for (int jj = 0; jj < 4; jj++) {
                int j = 4 * g + jj;
                if (j <= i) {
                    r1 += P[i * SRP + j] + EPSF * colK[j];
                    r2 += P[j * SRP + i] + EPSF * colQ[j];
                }
            }
            float b1 = 0.f, b2 = 0.f;
#pragma unroll
            for (int u = 0; u < 4; u++) {
                int d = 4 * g + u;
                b1 += (bf2f(sqB[i * SB + d]) + EPSF) * (pk[d] + EPSF);
                b2 += (bf2f(skB[i * SB + d]) + EPSF) * (pq[d] + EPSF);
            }
#pragma unroll
            for (int m = 1; m < 16; m <<= 1) {
                r1 += __shfl_xor(r1, m, 64);
                r2 += __shfl_xor(r2, m, 64);
                b1 += __shfl_xor(b1, m, 64);
                b2 += __shfl_xor(b2, m, 64);
            }
            if (g == 0) {
                float nf = (float)(c * C + i + 1);
                lsi[i] = nf / (b1 + r1);
                lso[i] = nf / (b2 + r2);
            }
        }
        __syncthreads();

        // ---- E: rw1/rw2 triangular (waves 0-7, 8/row) + SKso (wave 8) + SQsi (wave 9) ----
        if (t < 512) {
            int i = t >> 3, g = t & 7;
            float a1 = 0.f, a2 = 0.f;
#pragma unroll
            for (int jj = 0; jj < 8; jj++) {
                int j = 8 * g + jj;
                if (j <= i) {
                    a1 += lso[j] * (P[i * SRP + j] + EPSF * colK[j]);
                    a2 += lsi[j] * (P[j * SRP + i] + EPSF * colQ[j]);
                }
            }
#pragma unroll
            for (int m = 1; m < 8; m <<= 1) {
                a1 += __shfl_xor(a1, m, 64);
                a2 += __shfl_xor(a2, m, 64);
            }
            if (g == 0) { rw1a[i] = a1; rw2a[i] = a2; }
        } else if (t < 576) {
            int d = t - 512; float v = 0.f;
            for (int i = 0; i < C; i++) v += bf2f(skT[d * SB + i]) * lso[i];
            SKso[d] = v;
        } else if (t < 640) {
            int d = t - 576; float v = 0.f;
            for (int i = 0; i < C; i++) v += bf2f(sqB[i * SB + d]) * lsi[i];
            SQsi[d] = v;
        }
        __syncthreads();

        // ---- F: conserved sink/source, e, sal (16/row) ----
        {
            int i = t >> 4, g = t & 15;
            float b1 = 0.f, b2 = 0.f;
#pragma unroll
            for (int u = 0; u < 4; u++) {
                int d = 4 * g + u;
                b1 += (bf2f(sqB[i * SB + d]) + EPSF) * (pks[d] + EPSF);
                b2 += (bf2f(skB[i * SB + d]) + EPSF) * (pqs[d] + EPSF);
            }
#pragma unroll
            for (int m = 1; m < 16; m <<= 1) {
                b1 += __shfl_xor(b1, m, 64);
                b2 += __shfl_xor(b2, m, 64);
            }
            if (g == 0) {
                float nf = (float)(c * C + i + 1);
                float cs  = (b1 + rw1a[i]) / nf;
                float csr = fminf(fmaxf((b2 + rw2a[i]) / nf, -1.f), 1.f);
                le[i]  = __expf(csr);
                s2l[i] = lsi[i] / nf * sigf(cs);
            }
        }
        __syncthreads();

        // ---- G: e-scan + scomp (wave 0) ----
        if (t < 64) {
            float Tc = Tcum;
            float run = le[t];
#pragma unroll
            for (int off = 1; off < 64; off <<= 1) {
                float o = __shfl_up(run, off, 64);
                if (t >= off) run += o;
            }
            lsc[t] = le[t] / (Tc + run) * (float)(c * C + t + 1);
            if (t == 63) Tcum = Tc + run;
        }
        __syncthreads();

        // ---- H: stB = masked P*scomp (into skB), scale skT by scomp, kvB <- master ----
        {
            int i = t >> 4, x0 = dA;
            float p0 = P[i * SRP + x0 + 0], p1 = P[i * SRP + x0 + 1];
            float p2 = P[i * SRP + x0 + 2], p3 = P[i * SRP + x0 + 3];
            float m0 = (x0 + 0 <= i) ? p0 * lsc[x0 + 0] : 0.f;
            float m1 = (x0 + 1 <= i) ? p1 * lsc[x0 + 1] : 0.f;
            float m2 = (x0 + 2 <= i) ? p2 * lsc[x0 + 2] : 0.f;
            float m3 = (x0 + 3 <= i) ? p3 * lsc[x0 + 3] : 0.f;
            *(uint2*)&skB[i * SB + x0] = make_uint2(pack2(m0, m1), pack2(m2, m3));

            uint2 kd = *(uint2*)&skT[i * SB + x0];   // i plays the role of d here
            float t0 = bf2f((unsigned short)(kd.x & 0xffff)) * lsc[x0 + 0];
            float t1 = bf2f((unsigned short)(kd.x >> 16))    * lsc[x0 + 1];
            float t2 = bf2f((unsigned short)(kd.y & 0xffff)) * lsc[x0 + 2];
            float t3 = bf2f((unsigned short)(kd.y >> 16))    * lsc[x0 + 3];
            *(uint2*)&skT[i * SB + x0] = make_uint2(pack2(t0, t1), pack2(t2, t3));

            float4 mv = *(const float4*)&master[i * SM + x0];   // i = m row
            *(uint2*)&kvB[i * SB + x0] = make_uint2(pack2(mv.x, mv.y), pack2(mv.z, mv.w));
        }
        __syncthreads();

        // ---- I: mm1 (sq·KVp) + mm2 (stB·v) + KV-chunk MFMA; out + master/prefix update ----
        {
            f32x4 acc = {0, 0, 0, 0}, kva = {0, 0, 0, 0};
#pragma unroll
            for (int kk = 0; kk < 64; kk += 32) {
                short8 a1v = *(const short8*)&sqB[(I0 + mf) * SB + kk + qq * 8];
                short8 b1v = *(const short8*)&kvB[(J0 + mf) * SB + kk + qq * 8];
                acc = MFMA16(a1v, b1v, acc);
                short8 a2v = *(const short8*)&skB[(I0 + mf) * SB + kk + qq * 8];  // stB
                short8 b2v = *(const short8*)&vT [(J0 + mf) * SB + kk + qq * 8];
                acc = MFMA16(a2v, b2v, acc);
                short8 a3v = *(const short8*)&vT [(I0 + mf) * SB + kk + qq * 8];
                short8 b3v = *(const short8*)&skT[(J0 + mf) * SB + kk + qq * 8];  // scaled
                kva = MFMA16(a3v, b3v, kva);
            }
#pragma unroll
            for (int r = 0; r < 4; r++) {
                int io = I0 + 4 * qq + r;
                Out[gidx(n, c * C + io, h, J0 + mf)] = acc[r] * s2l[io];
                master[io * SM + J0 + mf] += kva[r];     // wave-private tile: no race
            }
        }
        if (t < 64)       pk [t]       += SKc [t];
        else if (t < 128) pq [t - 64]  += SQc [t - 64];
        else if (t < 192) pks[t - 128] += SKso[t - 128];
        else if (t < 256) pqs[t - 192] += SQsi[t - 192];
        __syncthreads();
    }
}

extern "C" void kernel_launch(void* const* d_in, const int* in_sizes, int n_in,
                              void* d_out, int out_size, void* d_ws, size_t ws_size,
                              hipStream_t stream) {
    const float* Q = (const float*)d_in[0];
    const float* K = (const float*)d_in[1];
    const float* V = (const float*)d_in[2];
    float* Out = (float*)d_out;
    k_mega<<<dim3(S), dim3(1024), 0, stream>>>(Q, K, V, Out);
}

// Round 10
// 106.060 us; speedup vs baseline: 3.1511x; 3.1511x over previous
//
#include <hip/hip_runtime.h>
#include <math.h>

// Problem constants (fixed by reference setup_inputs)
constexpr int Nn = 2, Hh = 8, Ll = 2048, Dd = 64;
constexpr int S  = Nn * Hh;      // 16 sequences
constexpr int C  = 64;           // chunk length
constexpr int NC = Ll / C;       // 32 chunks/seq
constexpr int SC = S * NC;       // 512 chunk-blocks

constexpr int SB  = 72;          // bf16 LDS row stride (144 B rows, 16B-aligned)
constexpr int SRP = 65;          // fp32 score-matrix stride
constexpr int SS8 = 9;           // stride for 8-partial row-sum scratch

#define EPSF 1e-6f

typedef __attribute__((ext_vector_type(8))) short short8;
typedef __attribute__((ext_vector_type(4))) float f32x4;
#define MFMA16(a, b, c) __builtin_amdgcn_mfma_f32_16x16x32_bf16(a, b, c, 0, 0, 0)

__device__ __forceinline__ float sigf(float x) { return 1.0f / (1.0f + expf(-x)); }

__device__ __forceinline__ float waveRed(float v) {
#pragma unroll
    for (int off = 32; off > 0; off >>= 1) v += __shfl_xor(v, off, 64);
    return v;
}

__device__ __forceinline__ int gidx(int n, int l, int h, int d) {
    return ((n * Ll + l) * Hh + h) * Dd + d;
}

__device__ __forceinline__ float fc(const float4& v, int u) { return ((const float*)&v)[u]; }

__device__ __forceinline__ unsigned short f2bf(float x) {
    unsigned int u = __float_as_uint(x);
    unsigned int r = (u + 0x7fffu + ((u >> 16) & 1u)) >> 16;   // RNE
    return (unsigned short)r;
}
__device__ __forceinline__ unsigned int pack2(float lo, float hi) {
    return (unsigned int)f2bf(lo) | ((unsigned int)f2bf(hi) << 16);
}
__device__ __forceinline__ float bf2f(unsigned short u) {
    return __uint_as_float(((unsigned int)u) << 16);
}
__device__ __forceinline__ float lo16(unsigned int x) { return __uint_as_float(x << 16); }
__device__ __forceinline__ float hi16(unsigned int x) { return __uint_as_float(x & 0xffff0000u); }
__device__ __forceinline__ void unpack8(const uint4& v, float* o) {
    o[0] = lo16(v.x); o[1] = hi16(v.x); o[2] = lo16(v.y); o[3] = hi16(v.y);
    o[4] = lo16(v.z); o[5] = hi16(v.z); o[6] = lo16(v.w); o[7] = hi16(v.w);
}

// K1: stage — sigmoid ONCE, emit bf16 Qb/Kb (natural [i][d]), Kt/Vt (transposed [d][i]),
//     and per-chunk sums SK/SQ.
__global__ __launch_bounds__(256) void k_stage(const float* __restrict__ Q,
                                               const float* __restrict__ K,
                                               const float* __restrict__ V,
                                               unsigned short* __restrict__ Qb,
                                               unsigned short* __restrict__ Kb,
                                               unsigned short* __restrict__ Kt,
                                               unsigned short* __restrict__ Vt,
                                               float* __restrict__ SK,
                                               float* __restrict__ SQ) {
    __shared__ __align__(16) unsigned short skL[C * SB];
    __shared__ float scr[2048];
    int b = blockIdx.x, s = b / NC, c = b % NC;
    int n = s / Hh, h = s % Hh, t = threadIdx.x;
    int d0 = (4 * t) & 63, ig = t >> 4;
    size_t base = (size_t)b * 4096;
    float psk[4] = {0, 0, 0, 0}, psq[4] = {0, 0, 0, 0};
#pragma unroll
    for (int j = 0; j < 4; j++) {
        int i = ig + 16 * j;
        int id = gidx(n, c * C + i, h, d0);
        float4 q4 = *(const float4*)&Q[id];
        float4 k4 = *(const float4*)&K[id];
        float a0 = sigf(q4.x), a1 = sigf(q4.y), a2 = sigf(q4.z), a3 = sigf(q4.w);
        float b0 = sigf(k4.x), b1 = sigf(k4.y), b2 = sigf(k4.z), b3 = sigf(k4.w);
        uint2 pq2 = make_uint2(pack2(a0, a1), pack2(a2, a3));
        uint2 pk2 = make_uint2(pack2(b0, b1), pack2(b2, b3));
        *(uint2*)&Qb[base + i * 64 + d0] = pq2;
        *(uint2*)&Kb[base + i * 64 + d0] = pk2;
        *(uint2*)&skL[i * SB + d0] = pk2;
        psq[0] += a0; psq[1] += a1; psq[2] += a2; psq[3] += a3;
        psk[0] += b0; psk[1] += b1; psk[2] += b2; psk[3] += b3;
    }
#pragma unroll
    for (int r = 0; r < 4; r++) {
        scr[ig * 64 + d0 + r] = psk[r];
        scr[1024 + ig * 64 + d0 + r] = psq[r];
    }
    __syncthreads();
    if (t < 64) {
        float v = 0.f;
        for (int g = 0; g < 16; g++) v += scr[g * 64 + t];
        SK[b * 64 + t] = v;
    } else if (t < 128) {
        int d = t - 64; float v = 0.f;
        for (int g = 0; g < 16; g++) v += scr[1024 + g * 64 + d];
        SQ[b * 64 + d] = v;
    }
    // transposed outputs: K from LDS, V from global
    {
        int i0 = (t & 15) * 4, dt = (t >> 4) * 4;
        uint2 kr[4]; float4 vr[4];
#pragma unroll
        for (int r = 0; r < 4; r++) {
            kr[r] = *(const uint2*)&skL[(i0 + r) * SB + dt];
            vr[r] = *(const float4*)&V[gidx(n, c * C + i0 + r, h, dt)];
        }
#pragma unroll
        for (int u = 0; u < 4; u++) {
            unsigned int e0 = (u < 2 ? kr[0].x : kr[0].y), e1 = (u < 2 ? kr[1].x : kr[1].y);
            unsigned int e2 = (u < 2 ? kr[2].x : kr[2].y), e3 = (u < 2 ? kr[3].x : kr[3].y);
            int sh = (u & 1) * 16;
            unsigned int lo = ((e0 >> sh) & 0xffffu) | (((e1 >> sh) & 0xffffu) << 16);
            unsigned int hi = ((e2 >> sh) & 0xffffu) | (((e3 >> sh) & 0xffffu) << 16);
            *(uint2*)&Kt[base + (dt + u) * 64 + i0] = make_uint2(lo, hi);
            *(uint2*)&Vt[base + (dt + u) * 64 + i0] = make_uint2(
                pack2(fc(vr[0], u), fc(vr[1], u)), pack2(fc(vr[2], u), fc(vr[3], u)));
        }
    }
}

// K2: pass1 — row-copy bf16 staging, MFMA P (LDS only), si/so, rw1/rw2, SKso/SQsi.
__global__ __launch_bounds__(256) void k_pass1(const unsigned short* __restrict__ Qb,
                                               const unsigned short* __restrict__ Kb,
                                               const float* __restrict__ SK,
                                               const float* __restrict__ SQ,
                                               float* __restrict__ SKso,
                                               float* __restrict__ SQsi,
                                               float* __restrict__ si_g,
                                               float* __restrict__ rw1_g,
                                               float* __restrict__ rw2_g) {
    __shared__ __align__(16) unsigned short sqB[C * SB];
    __shared__ __align__(16) unsigned short skB[C * SB];
    __shared__ float P[C * SRP];
    __shared__ float scrA[C * SS8], scrB[C * SS8];
    __shared__ float colK[C], colQ[C], pk[Dd], pq[Dd], lsi[C], lso[C];
    int b = blockIdx.x, s = b / NC, c = b % NC, t = threadIdx.x;
    size_t base = (size_t)b * 4096;

#pragma unroll
    for (int j = 0; j < 2; j++) {
        int flat = 8 * t + 2048 * j, i = flat >> 6, d0 = flat & 63;
        uint4 xq = *(const uint4*)&Qb[base + flat];
        uint4 xk = *(const uint4*)&Kb[base + flat];
        *(uint4*)&sqB[i * SB + d0] = xq;
        *(uint4*)&skB[i * SB + d0] = xk;
        float qa[8], ka[8];
        unpack8(xq, qa); unpack8(xk, ka);
        float sq = 0.f, sk = 0.f;
#pragma unroll
        for (int u = 0; u < 8; u++) { sq += qa[u]; sk += ka[u]; }
        scrB[i * SS8 + (d0 >> 3)] = sq;
        scrA[i * SS8 + (d0 >> 3)] = sk;
    }
    {   // cross-chunk prefix partials (4 groups)
        int d = t & 63, g = t >> 6;
        float pa = 0.f, pb = 0.f;
        for (int cp = g; cp < c; cp += 4) {
            pa += SK[(s * NC + cp) * 64 + d];
            pb += SQ[(s * NC + cp) * 64 + d];
        }
        P[2048 + g * 64 + d] = pa;
        P[2304 + g * 64 + d] = pb;
    }
    __syncthreads();
    if (t < 64) {
        float v = 0.f;
#pragma unroll
        for (int u = 0; u < 8; u++) v += scrA[t * SS8 + u];
        colK[t] = v;
    } else if (t < 128) {
        int i = t - 64; float v = 0.f;
#pragma unroll
        for (int u = 0; u < 8; u++) v += scrB[i * SS8 + u];
        colQ[i] = v;
    } else if (t < 192) {
        int d = t - 128;
        pk[d] = P[2048 + d] + P[2112 + d] + P[2176 + d] + P[2240 + d];
    } else {
        int d = t - 192;
        pq[d] = P[2304 + d] + P[2368 + d] + P[2432 + d] + P[2496 + d];
    }
    __syncthreads();

    // MFMA: P = sq · sk^T
    {
        int w = t >> 6, lane = t & 63, m = lane & 15, q = lane >> 4;
        f32x4 acc[4] = {{0,0,0,0},{0,0,0,0},{0,0,0,0},{0,0,0,0}};
#pragma unroll
        for (int kk = 0; kk < 64; kk += 32) {
            short8 a = *(const short8*)&sqB[(16 * w + m) * SB + kk + q * 8];
#pragma unroll
            for (int J = 0; J < 4; J++) {
                short8 bb = *(const short8*)&skB[(16 * J + m) * SB + kk + q * 8];
                acc[J] = MFMA16(a, bb, acc[J]);
            }
        }
#pragma unroll
        for (int J = 0; J < 4; J++)
#pragma unroll
            for (int r = 0; r < 4; r++)
                P[(16 * w + 4 * q + r) * SRP + 16 * J + m] = acc[J][r];
    }
    __syncthreads();

    if (t < 64) {
        int i = t, l = c * C + i;
        float r1 = 0.f, r2 = 0.f;
        for (int j = 0; j <= i; j++) {
            r1 += P[i * SRP + j] + EPSF * colK[j];
            r2 += P[j * SRP + i] + EPSF * colQ[j];
        }
        float b1 = 0.f, b2 = 0.f;
        for (int d = 0; d < Dd; d++) {
            b1 += (bf2f(sqB[i * SB + d]) + EPSF) * (pk[d] + EPSF);
            b2 += (bf2f(skB[i * SB + d]) + EPSF) * (pq[d] + EPSF);
        }
        float nf = (float)(l + 1);
        float siF = nf / (b1 + r1), soF = nf / (b2 + r2);
        si_g[s * Ll + l] = siF;
        lsi[i] = siF; lso[i] = soF;
    }
    __syncthreads();

    if (t < 64) {
        int i = t; float v = 0.f;
        for (int j = 0; j <= i; j++) v += lso[j] * (P[i * SRP + j] + EPSF * colK[j]);
        rw1_g[s * Ll + c * C + i] = v;
    } else if (t < 128) {
        int i = t - 64; float v = 0.f;
        for (int j = 0; j <= i; j++) v += lsi[j] * (P[j * SRP + i] + EPSF * colQ[j]);
        rw2_g[s * Ll + c * C + i] = v;
    } else if (t < 192) {
        int d = t - 128; float v = 0.f;
        for (int i = 0; i < C; i++) v += bf2f(skB[i * SB + d]) * lso[i];
        SKso[b * 64 + d] = v;
    } else {
        int d = t - 192; float v = 0.f;
        for (int i = 0; i < C; i++) v += bf2f(sqB[i * SB + d]) * lsi[i];
        SQsi[b * 64 + d] = v;
    }
}

// K3: light pass2 — prefix + direct bf16 matvec.
__global__ __launch_bounds__(256) void k_pass2(const unsigned short* __restrict__ Qb,
                                               const unsigned short* __restrict__ Kb,
                                               const float* __restrict__ SKso,
                                               const float* __restrict__ SQsi,
                                               const float* __restrict__ si_g,
                                               const float* __restrict__ rw1_g,
                                               const float* __restrict__ rw2_g,
                                               float* __restrict__ s2_g,
                                               float* __restrict__ e_g,
                                               float* __restrict__ ecum_g,
                                               float* __restrict__ Tcs) {
    __shared__ float scr[512];
    __shared__ float pks[Dd], pqs[Dd], le[C];
    int b = blockIdx.x, s = b / NC, c = b % NC, t = threadIdx.x;

    {
        int d = t & 63, g = t >> 6;
        float pa = 0.f, pb = 0.f;
        for (int cp = g; cp < c; cp += 4) {
            pa += SKso[(s * NC + cp) * 64 + d];
            pb += SQsi[(s * NC + cp) * 64 + d];
        }
        scr[g * 64 + d] = pa;
        scr[256 + g * 64 + d] = pb;
    }
    __syncthreads();
    if (t < 64) pks[t] = scr[t] + scr[64 + t] + scr[128 + t] + scr[192 + t];
    else if (t < 128) {
        int d = t - 64;
        pqs[d] = scr[256 + d] + scr[320 + d] + scr[384 + d] + scr[448 + d];
    }
    __syncthreads();

    int i = t >> 2, g = t & 3, l = c * C + i;
    float b1 = 0.f, b2 = 0.f;
    size_t base = (size_t)b * 4096 + i * 64 + g * 16;
#pragma unroll
    for (int j = 0; j < 2; j++) {
        uint4 xq = *(const uint4*)&Qb[base + 8 * j];
        uint4 xk = *(const uint4*)&Kb[base + 8 * j];
        float qa[8], ka[8];
        unpack8(xq, qa); unpack8(xk, ka);
        int d = g * 16 + 8 * j;
#pragma unroll
        for (int u = 0; u < 8; u++) {
            b1 += (qa[u] + EPSF) * (pks[d + u] + EPSF);
            b2 += (ka[u] + EPSF) * (pqs[d + u] + EPSF);
        }
    }
    b1 += __shfl_xor(b1, 1, 64); b1 += __shfl_xor(b1, 2, 64);
    b2 += __shfl_xor(b2, 1, 64); b2 += __shfl_xor(b2, 2, 64);
    if (g == 0) {
        float nf = (float)(l + 1);
        float cs  = (b1 + rw1_g[s * Ll + l]) / nf;
        float csr = (b2 + rw2_g[s * Ll + l]) / nf;
        csr = fminf(fmaxf(csr, -1.f), 1.f);
        float e = expf(csr);
        float sal = 1.0f / (1.0f + expf(-cs));
        s2_g[s * Ll + l] = si_g[s * Ll + l] / nf * sal;
        e_g[s * Ll + l] = e;
        le[i] = e;
    }
    __syncthreads();
    if (t < 64) {
        float run = le[t];
#pragma unroll
        for (int off = 1; off < 64; off <<= 1) {
            float o = __shfl_up(run, off, 64);
            if (t >= off) run += o;
        }
        ecum_g[s * Ll + c * C + t] = run;
        if (t == 63) Tcs[b] = run;
    }
}

// K4: scomp + MFMA chunk KV^T[m][d] (row-copy staging from Kt/Vt).
__global__ __launch_bounds__(256) void k_kv(const unsigned short* __restrict__ Kt,
                                            const unsigned short* __restrict__ Vt,
                                            const float* __restrict__ e_g,
                                            const float* __restrict__ ecum_g,
                                            const float* __restrict__ Tcs,
                                            float* __restrict__ scomp_g,
                                            float* __restrict__ KVT) {
    __shared__ __align__(16) unsigned short skT[C * SB];   // [d][i]
    __shared__ __align__(16) unsigned short vsT[C * SB];   // [m][i] scomp-scaled
    __shared__ float lsc[C];
    __shared__ float pcsv;
    int b = blockIdx.x, s = b / NC, c = b % NC, t = threadIdx.x;
    if (t < 64) {
        float v = (t < c) ? Tcs[s * NC + t] : 0.f;
        v = waveRed(v);
        if (t == 0) pcsv = v;
    }
    __syncthreads();
    if (t < 64) {
        int l = c * C + t;
        float ls = e_g[s * Ll + l] / (pcsv + ecum_g[s * Ll + l]) * (float)(l + 1);
        lsc[t] = ls;
        scomp_g[s * Ll + l] = ls;
    }
    __syncthreads();

    size_t base = (size_t)b * 4096;
#pragma unroll
    for (int j = 0; j < 2; j++) {
        int flat = 8 * t + 2048 * j, dR = flat >> 6, i0 = flat & 63;
        *(uint4*)&skT[dR * SB + i0] = *(const uint4*)&Kt[base + flat];
        uint4 vv = *(const uint4*)&Vt[base + flat];
        float x[8];
        unpack8(vv, x);
#pragma unroll
        for (int u = 0; u < 8; u++) x[u] *= lsc[i0 + u];
        uint4 o;
        o.x = pack2(x[0], x[1]); o.y = pack2(x[2], x[3]);
        o.z = pack2(x[4], x[5]); o.w = pack2(x[6], x[7]);
        *(uint4*)&vsT[dR * SB + i0] = o;
    }
    __syncthreads();

    {   // MFMA: KVT[m][d] = sum_i vsT[m][i] * skT[d][i]
        int w = t >> 6, lane = t & 63, m = lane & 15, q = lane >> 4;
        f32x4 acc[4] = {{0,0,0,0},{0,0,0,0},{0,0,0,0},{0,0,0,0}};
#pragma unroll
        for (int kk = 0; kk < 64; kk += 32) {
            short8 a = *(const short8*)&vsT[(16 * w + m) * SB + kk + q * 8];
#pragma unroll
            for (int J = 0; J < 4; J++) {
                short8 bb = *(const short8*)&skT[(16 * J + m) * SB + kk + q * 8];
                acc[J] = MFMA16(a, bb, acc[J]);
            }
        }
#pragma unroll
        for (int J = 0; J < 4; J++)
#pragma unroll
            for (int r = 0; r < 4; r++)
                KVT[(size_t)b * 4096 + (16 * w + 4 * q + r) * 64 + 16 * J + m] = acc[J][r];
    }
}

// K5: exclusive chunk-prefix of KVT. grid=256.
__global__ __launch_bounds__(256) void k_prefixKV(float* __restrict__ KVT) {
    int bx = blockIdx.x, s = bx >> 4, sub = bx & 15;
    int e0 = sub * 256 + threadIdx.x;
    float x[NC];
#pragma unroll
    for (int cp = 0; cp < NC; cp++)
        x[cp] = KVT[(size_t)(s * NC + cp) * 4096 + e0];
    float r = 0.f;
#pragma unroll
    for (int cp = 0; cp < NC; cp++) {
        float tv = x[cp];
        KVT[(size_t)(s * NC + cp) * 4096 + e0] = r;
        r += tv;
    }
}

// K6: final — P recomputed via MFMA (no Pg); kvB overlaid on skB after P pass.
__global__ __launch_bounds__(256) void k_final(const unsigned short* __restrict__ Qb,
                                               const unsigned short* __restrict__ Kb,
                                               const unsigned short* __restrict__ Vt,
                                               const float* __restrict__ s2_g,
                                               const float* __restrict__ scomp_g,
                                               const float* __restrict__ KVT,
                                               float* __restrict__ Out) {
    __shared__ __align__(16) unsigned short sqB[C * SB];    // [i][d]
    __shared__ __align__(16) unsigned short skB[C * SB];    // sk rows; later kvB [m][d]
    __shared__ __align__(16) unsigned short vsT[C * SB];    // [m][j] raw v
    __shared__ __align__(16) unsigned short stB[C * SB];    // [i][j] masked P*scomp
    __shared__ float lsc[C], s2l[C];
    int b = blockIdx.x, s = b / NC, c = b % NC;
    int n = s / Hh, h = s % Hh, t = threadIdx.x;
    int w = t >> 6, lane = t & 63, mf = lane & 15, qq = lane >> 4;
    int I0 = 16 * w;

    if (t < 64) lsc[t] = scomp_g[s * Ll + c * C + t];
    else if (t < 128) s2l[t - 64] = s2_g[s * Ll + c * C + (t - 64)];

    // early KVT loads (hidden behind staging + P-MFMA)
    float4 kvr[4];
#pragma unroll
    for (int j = 0; j < 4; j++)
        kvr[j] = *(const float4*)&KVT[(size_t)b * 4096 + 4 * t + 1024 * j];

    size_t base = (size_t)b * 4096;
#pragma unroll
    for (int j = 0; j < 2; j++) {
        int flat = 8 * t + 2048 * j, i = flat >> 6, d0 = flat & 63;
        *(uint4*)&sqB[i * SB + d0] = *(const uint4*)&Qb[base + flat];
        *(uint4*)&skB[i * SB + d0] = *(const uint4*)&Kb[base + flat];
        *(uint4*)&vsT[i * SB + d0] = *(const uint4*)&Vt[base + flat];
    }
    __syncthreads();

    // P recompute: wave w owns row-block I0; mask+scale -> stB
    {
        f32x4 acc[4] = {{0,0,0,0},{0,0,0,0},{0,0,0,0},{0,0,0,0}};
#pragma unroll
        for (int kk = 0; kk < 64; kk += 32) {
            short8 a = *(const short8*)&sqB[(I0 + mf) * SB + kk + qq * 8];
#pragma unroll
            for (int J = 0; J < 4; J++) {
                short8 bb = *(const short8*)&skB[(16 * J + mf) * SB + kk + qq * 8];
                acc[J] = MFMA16(a, bb, acc[J]);
            }
        }
#pragma unroll
        for (int J = 0; J < 4; J++)
#pragma unroll
            for (int r = 0; r < 4; r++) {
                int i = I0 + 4 * qq + r, jj = 16 * J + mf;
                float v = (jj <= i) ? acc[J][r] * lsc[jj] : 0.f;
                stB[i * SB + jj] = f2bf(v);
            }
    }
    __syncthreads();   // skB reads done; stB ready

    // overlay kvB (= prefix KV rows [m][d]) onto skB
#pragma unroll
    for (int j = 0; j < 4; j++) {
        int flat = 4 * t + 1024 * j, i = flat >> 6, d0 = flat & 63;
        *(uint2*)&skB[i * SB + d0] = make_uint2(pack2(kvr[j].x, kvr[j].y),
                                                pack2(kvr[j].z, kvr[j].w));
    }
    __syncthreads();

    f32x4 acc[4] = {{0,0,0,0},{0,0,0,0},{0,0,0,0},{0,0,0,0}};
#pragma unroll
    for (int kk = 0; kk < 64; kk += 32) {   // mm1: sq · KVp ; mm2: stB · v
        short8 a1 = *(const short8*)&sqB[(I0 + mf) * SB + kk + qq * 8];
        short8 a2 = *(const short8*)&stB[(I0 + mf) * SB + kk + qq * 8];
#pragma unroll
        for (int J = 0; J < 4; J++) {
            short8 b1 = *(const short8*)&skB[(16 * J + mf) * SB + kk + qq * 8];
            acc[J] = MFMA16(a1, b1, acc[J]);
            short8 b2 = *(const short8*)&vsT[(16 * J + mf) * SB + kk + qq * 8];
            acc[J] = MFMA16(a2, b2, acc[J]);
        }
    }
#pragma unroll
    for (int J = 0; J < 4; J++)
#pragma unroll
        for (int r = 0; r < 4; r++) {
            int io = I0 + 4 * qq + r;
            Out[gidx(n, c * C + io, h, 16 * J + mf)] = acc[J][r] * s2l[io];
        }
}

extern "C" void kernel_launch(void* const* d_in, const int* in_sizes, int n_in,
                              void* d_out, int out_size, void* d_ws, size_t ws_size,
                              hipStream_t stream) {
    const float* Q = (const float*)d_in[0];
    const float* K = (const float*)d_in[1];
    const float* V = (const float*)d_in[2];
    float* Out = (float*)d_out;

    float* ws    = (float*)d_ws;
    float* SK    = ws;                  // SC*64
    float* SQ    = SK    + SC * 64;
    float* SKso  = SQ    + SC * 64;
    float* SQsi  = SKso  + SC * 64;
    float* si_g  = SQsi  + SC * 64;     // S*Ll each
    float* rw1_g = si_g  + S * Ll;
    float* rw2_g = rw1_g + S * Ll;
    float* s2_g  = rw2_g + S * Ll;
    float* e_g   = s2_g  + S * Ll;
    float* ecum_g= e_g   + S * Ll;
    float* scomp = ecum_g+ S * Ll;
    float* Tcs   = scomp + S * Ll;      // SC
    float* KVT   = Tcs   + SC;          // SC*4096
    unsigned short* Qb = (unsigned short*)(KVT + (size_t)SC * 4096);   // SC*4096 bf16 each
    unsigned short* Kb = Qb + (size_t)SC * 4096;
    unsigned short* Kt = Kb + (size_t)SC * 4096;
    unsigned short* Vt = Kt + (size_t)SC * 4096;

    k_stage<<<SC, 256, 0, stream>>>(Q, K, V, Qb, Kb, Kt, Vt, SK, SQ);
    k_pass1<<<SC, 256, 0, stream>>>(Qb, Kb, SK, SQ, SKso, SQsi, si_g, rw1_g, rw2_g);
    k_pass2<<<SC, 256, 0, stream>>>(Qb, Kb, SKso, SQsi, si_g, rw1_g, rw2_g, s2_g, e_g, ecum_g, Tcs);
    k_kv<<<SC, 256, 0, stream>>>(Kt, Vt, e_g, ecum_g, Tcs, scomp, KVT);
    k_prefixKV<<<256, 256, 0, stream>>>(KVT);
    k_final<<<SC, 256, 0, stream>>>(Qb, Kb, Vt, s2_g, scomp, KVT, Out);
}

// Round 11
// 103.384 us; speedup vs baseline: 3.2327x; 1.0259x over previous
//
#include <hip/hip_runtime.h>
#include <math.h>

// Problem constants (fixed by reference setup_inputs)
constexpr int Nn = 2, Hh = 8, Ll = 2048, Dd = 64;
constexpr int S  = Nn * Hh;      // 16 sequences
constexpr int C  = 64;           // chunk length
constexpr int NC = Ll / C;       // 32 chunks/seq
constexpr int SC = S * NC;       // 512 chunk-blocks

constexpr int SB  = 72;          // bf16 LDS row stride (144 B rows, 16B-aligned)
constexpr int SRP = 65;          // fp32 score-matrix stride
constexpr int SS8 = 9;           // stride for 8-partial row-sum scratch

#define EPSF 1e-6f

typedef __attribute__((ext_vector_type(8))) short short8;
typedef __attribute__((ext_vector_type(4))) float f32x4;
#define MFMA16(a, b, c) __builtin_amdgcn_mfma_f32_16x16x32_bf16(a, b, c, 0, 0, 0)

__device__ __forceinline__ float rcpf(float x) { return __builtin_amdgcn_rcpf(x); }
// fast sigmoid: v_exp_f32 + v_rcp_f32 (~1ulp each; feeds bf16 — ample).
// R9 measured absmax identical with __expf vs expf.
__device__ __forceinline__ float sigf(float x) { return rcpf(1.0f + __expf(-x)); }

__device__ __forceinline__ float waveRed(float v) {
#pragma unroll
    for (int off = 32; off > 0; off >>= 1) v += __shfl_xor(v, off, 64);
    return v;
}

__device__ __forceinline__ int gidx(int n, int l, int h, int d) {
    return ((n * Ll + l) * Hh + h) * Dd + d;
}

__device__ __forceinline__ float fc(const float4& v, int u) { return ((const float*)&v)[u]; }

__device__ __forceinline__ unsigned short f2bf(float x) {
    unsigned int u = __float_as_uint(x);
    unsigned int r = (u + 0x7fffu + ((u >> 16) & 1u)) >> 16;   // RNE
    return (unsigned short)r;
}
__device__ __forceinline__ unsigned int pack2(float lo, float hi) {
    return (unsigned int)f2bf(lo) | ((unsigned int)f2bf(hi) << 16);
}
__device__ __forceinline__ float bf2f(unsigned short u) {
    return __uint_as_float(((unsigned int)u) << 16);
}
__device__ __forceinline__ float lo16(unsigned int x) { return __uint_as_float(x << 16); }
__device__ __forceinline__ float hi16(unsigned int x) { return __uint_as_float(x & 0xffff0000u); }
__device__ __forceinline__ void unpack8(const uint4& v, float* o) {
    o[0] = lo16(v.x); o[1] = hi16(v.x); o[2] = lo16(v.y); o[3] = hi16(v.y);
    o[4] = lo16(v.z); o[5] = hi16(v.z); o[6] = lo16(v.w); o[7] = hi16(v.w);
}

// K1: stage — sigmoid ONCE, emit bf16 Qb/Kb (natural [i][d]), Kt/Vt (transposed [d][i]),
//     and per-chunk sums SK/SQ.
__global__ __launch_bounds__(256) void k_stage(const float* __restrict__ Q,
                                               const float* __restrict__ K,
                                               const float* __restrict__ V,
                                               unsigned short* __restrict__ Qb,
                                               unsigned short* __restrict__ Kb,
                                               unsigned short* __restrict__ Kt,
                                               unsigned short* __restrict__ Vt,
                                               float* __restrict__ SK,
                                               float* __restrict__ SQ) {
    __shared__ __align__(16) unsigned short skL[C * SB];
    __shared__ float scr[2048];
    int b = blockIdx.x, s = b / NC, c = b % NC;
    int n = s / Hh, h = s % Hh, t = threadIdx.x;
    int d0 = (4 * t) & 63, ig = t >> 4;
    size_t base = (size_t)b * 4096;
    float psk[4] = {0, 0, 0, 0}, psq[4] = {0, 0, 0, 0};
#pragma unroll
    for (int j = 0; j < 4; j++) {
        int i = ig + 16 * j;
        int id = gidx(n, c * C + i, h, d0);
        float4 q4 = *(const float4*)&Q[id];
        float4 k4 = *(const float4*)&K[id];
        float a0 = sigf(q4.x), a1 = sigf(q4.y), a2 = sigf(q4.z), a3 = sigf(q4.w);
        float b0 = sigf(k4.x), b1 = sigf(k4.y), b2 = sigf(k4.z), b3 = sigf(k4.w);
        uint2 pq2 = make_uint2(pack2(a0, a1), pack2(a2, a3));
        uint2 pk2 = make_uint2(pack2(b0, b1), pack2(b2, b3));
        *(uint2*)&Qb[base + i * 64 + d0] = pq2;
        *(uint2*)&Kb[base + i * 64 + d0] = pk2;
        *(uint2*)&skL[i * SB + d0] = pk2;
        psq[0] += a0; psq[1] += a1; psq[2] += a2; psq[3] += a3;
        psk[0] += b0; psk[1] += b1; psk[2] += b2; psk[3] += b3;
    }
#pragma unroll
    for (int r = 0; r < 4; r++) {
        scr[ig * 64 + d0 + r] = psk[r];
        scr[1024 + ig * 64 + d0 + r] = psq[r];
    }
    __syncthreads();
    if (t < 64) {
        float v = 0.f;
        for (int g = 0; g < 16; g++) v += scr[g * 64 + t];
        SK[b * 64 + t] = v;
    } else if (t < 128) {
        int d = t - 64; float v = 0.f;
        for (int g = 0; g < 16; g++) v += scr[1024 + g * 64 + d];
        SQ[b * 64 + d] = v;
    }
    // transposed outputs: K from LDS, V from global
    {
        int i0 = (t & 15) * 4, dt = (t >> 4) * 4;
        uint2 kr[4]; float4 vr[4];
#pragma unroll
        for (int r = 0; r < 4; r++) {
            kr[r] = *(const uint2*)&skL[(i0 + r) * SB + dt];
            vr[r] = *(const float4*)&V[gidx(n, c * C + i0 + r, h, dt)];
        }
#pragma unroll
        for (int u = 0; u < 4; u++) {
            unsigned int e0 = (u < 2 ? kr[0].x : kr[0].y), e1 = (u < 2 ? kr[1].x : kr[1].y);
            unsigned int e2 = (u < 2 ? kr[2].x : kr[2].y), e3 = (u < 2 ? kr[3].x : kr[3].y);
            int sh = (u & 1) * 16;
            unsigned int lo = ((e0 >> sh) & 0xffffu) | (((e1 >> sh) & 0xffffu) << 16);
            unsigned int hi = ((e2 >> sh) & 0xffffu) | (((e3 >> sh) & 0xffffu) << 16);
            *(uint2*)&Kt[base + (dt + u) * 64 + i0] = make_uint2(lo, hi);
            *(uint2*)&Vt[base + (dt + u) * 64 + i0] = make_uint2(
                pack2(fc(vr[0], u), fc(vr[1], u)), pack2(fc(vr[2], u), fc(vr[3], u)));
        }
    }
}

// K2: pass1 — row-copy bf16 staging, MFMA P (LDS only), si/so, rw1/rw2, SKso/SQsi.
//     Triangular scans spread 4-lanes-per-row (was 1-wave serial).
__global__ __launch_bounds__(256) void k_pass1(const unsigned short* __restrict__ Qb,
                                               const unsigned short* __restrict__ Kb,
                                               const float* __restrict__ SK,
                                               const float* __restrict__ SQ,
                                               float* __restrict__ SKso,
                                               float* __restrict__ SQsi,
                                               float* __restrict__ si_g,
                                               float* __restrict__ rw1_g,
                                               float* __restrict__ rw2_g) {
    __shared__ __align__(16) unsigned short sqB[C * SB];
    __shared__ __align__(16) unsigned short skB[C * SB];
    __shared__ float P[C * SRP];
    __shared__ float scrA[C * SS8], scrB[C * SS8];
    __shared__ float colK[C], colQ[C], pk[Dd], pq[Dd], lsi[C], lso[C];
    int b = blockIdx.x, s = b / NC, c = b % NC, t = threadIdx.x;
    size_t base = (size_t)b * 4096;

#pragma unroll
    for (int j = 0; j < 2; j++) {
        int flat = 8 * t + 2048 * j, i = flat >> 6, d0 = flat & 63;
        uint4 xq = *(const uint4*)&Qb[base + flat];
        uint4 xk = *(const uint4*)&Kb[base + flat];
        *(uint4*)&sqB[i * SB + d0] = xq;
        *(uint4*)&skB[i * SB + d0] = xk;
        float qa[8], ka[8];
        unpack8(xq, qa); unpack8(xk, ka);
        float sq = 0.f, sk = 0.f;
#pragma unroll
        for (int u = 0; u < 8; u++) { sq += qa[u]; sk += ka[u]; }
        scrB[i * SS8 + (d0 >> 3)] = sq;
        scrA[i * SS8 + (d0 >> 3)] = sk;
    }
    {   // cross-chunk prefix partials (4 groups)
        int d = t & 63, g = t >> 6;
        float pa = 0.f, pb = 0.f;
        for (int cp = g; cp < c; cp += 4) {
            pa += SK[(s * NC + cp) * 64 + d];
            pb += SQ[(s * NC + cp) * 64 + d];
        }
        P[2048 + g * 64 + d] = pa;
        P[2304 + g * 64 + d] = pb;
    }
    __syncthreads();
    if (t < 64) {
        float v = 0.f;
#pragma unroll
        for (int u = 0; u < 8; u++) v += scrA[t * SS8 + u];
        colK[t] = v;
    } else if (t < 128) {
        int i = t - 64; float v = 0.f;
#pragma unroll
        for (int u = 0; u < 8; u++) v += scrB[i * SS8 + u];
        colQ[i] = v;
    } else if (t < 192) {
        int d = t - 128;
        pk[d] = P[2048 + d] + P[2112 + d] + P[2176 + d] + P[2240 + d];
    } else {
        int d = t - 192;
        pq[d] = P[2304 + d] + P[2368 + d] + P[2432 + d] + P[2496 + d];
    }
    __syncthreads();

    // MFMA: P = sq · sk^T
    {
        int w = t >> 6, lane = t & 63, m = lane & 15, q = lane >> 4;
        f32x4 acc[4] = {{0,0,0,0},{0,0,0,0},{0,0,0,0},{0,0,0,0}};
#pragma unroll
        for (int kk = 0; kk < 64; kk += 32) {
            short8 a = *(const short8*)&sqB[(16 * w + m) * SB + kk + q * 8];
#pragma unroll
            for (int J = 0; J < 4; J++) {
                short8 bb = *(const short8*)&skB[(16 * J + m) * SB + kk + q * 8];
                acc[J] = MFMA16(a, bb, acc[J]);
            }
        }
#pragma unroll
        for (int J = 0; J < 4; J++)
#pragma unroll
            for (int r = 0; r < 4; r++)
                P[(16 * w + 4 * q + r) * SRP + 16 * J + m] = acc[J][r];
    }
    __syncthreads();

    // si/so: 4 lanes per row
    {
        int i = t >> 2, g = t & 3, l = c * C + i;
        float r1 = 0.f, r2 = 0.f;
        for (int jj = g; jj <= i; jj += 4) {
            r1 += P[i * SRP + jj] + EPSF * colK[jj];
            r2 += P[jj * SRP + i] + EPSF * colQ[jj];
        }
        float b1 = 0.f, b2 = 0.f;
#pragma unroll
        for (int u = 0; u < 16; u++) {
            int d = g * 16 + u;
            b1 += (bf2f(sqB[i * SB + d]) + EPSF) * (pk[d] + EPSF);
            b2 += (bf2f(skB[i * SB + d]) + EPSF) * (pq[d] + EPSF);
        }
        r1 += __shfl_xor(r1, 1, 64); r1 += __shfl_xor(r1, 2, 64);
        r2 += __shfl_xor(r2, 1, 64); r2 += __shfl_xor(r2, 2, 64);
        b1 += __shfl_xor(b1, 1, 64); b1 += __shfl_xor(b1, 2, 64);
        b2 += __shfl_xor(b2, 1, 64); b2 += __shfl_xor(b2, 2, 64);
        if (g == 0) {
            float nf = (float)(l + 1);
            float siF = nf * rcpf(b1 + r1), soF = nf * rcpf(b2 + r2);
            si_g[s * Ll + l] = siF;
            lsi[i] = siF; lso[i] = soF;
        }
    }
    __syncthreads();

    // rw1/rw2: 4 lanes per row
    {
        int i = t >> 2, g = t & 3;
        float a1 = 0.f, a2 = 0.f;
        for (int jj = g; jj <= i; jj += 4) {
            a1 += lso[jj] * (P[i * SRP + jj] + EPSF * colK[jj]);
            a2 += lsi[jj] * (P[jj * SRP + i] + EPSF * colQ[jj]);
        }
        a1 += __shfl_xor(a1, 1, 64); a1 += __shfl_xor(a1, 2, 64);
        a2 += __shfl_xor(a2, 1, 64); a2 += __shfl_xor(a2, 2, 64);
        if (g == 0) {
            rw1_g[s * Ll + c * C + i] = a1;
            rw2_g[s * Ll + c * C + i] = a2;
        }
    }
    // SKso/SQsi: 4 lanes per d (16 i's each)
    {
        int d = t >> 2, g = t & 3;
        float v1 = 0.f, v2 = 0.f;
#pragma unroll
        for (int u = 0; u < 16; u++) {
            int i = g * 16 + u;
            v1 += bf2f(skB[i * SB + d]) * lso[i];
            v2 += bf2f(sqB[i * SB + d]) * lsi[i];
        }
        v1 += __shfl_xor(v1, 1, 64); v1 += __shfl_xor(v1, 2, 64);
        v2 += __shfl_xor(v2, 1, 64); v2 += __shfl_xor(v2, 2, 64);
        if (g == 0) {
            SKso[b * 64 + d] = v1;
            SQsi[b * 64 + d] = v2;
        }
    }
}

// K3: light pass2 — prefix + direct bf16 matvec.
__global__ __launch_bounds__(256) void k_pass2(const unsigned short* __restrict__ Qb,
                                               const unsigned short* __restrict__ Kb,
                                               const float* __restrict__ SKso,
                                               const float* __restrict__ SQsi,
                                               const float* __restrict__ si_g,
                                               const float* __restrict__ rw1_g,
                                               const float* __restrict__ rw2_g,
                                               float* __restrict__ s2_g,
                                               float* __restrict__ e_g,
                                               float* __restrict__ ecum_g,
                                               float* __restrict__ Tcs) {
    __shared__ float scr[512];
    __shared__ float pks[Dd], pqs[Dd], le[C];
    int b = blockIdx.x, s = b / NC, c = b % NC, t = threadIdx.x;

    {
        int d = t & 63, g = t >> 6;
        float pa = 0.f, pb = 0.f;
        for (int cp = g; cp < c; cp += 4) {
            pa += SKso[(s * NC + cp) * 64 + d];
            pb += SQsi[(s * NC + cp) * 64 + d];
        }
        scr[g * 64 + d] = pa;
        scr[256 + g * 64 + d] = pb;
    }
    __syncthreads();
    if (t < 64) pks[t] = scr[t] + scr[64 + t] + scr[128 + t] + scr[192 + t];
    else if (t < 128) {
        int d = t - 64;
        pqs[d] = scr[256 + d] + scr[320 + d] + scr[384 + d] + scr[448 + d];
    }
    __syncthreads();

    int i = t >> 2, g = t & 3, l = c * C + i;
    float b1 = 0.f, b2 = 0.f;
    size_t base = (size_t)b * 4096 + i * 64 + g * 16;
#pragma unroll
    for (int j = 0; j < 2; j++) {
        uint4 xq = *(const uint4*)&Qb[base + 8 * j];
        uint4 xk = *(const uint4*)&Kb[base + 8 * j];
        float qa[8], ka[8];
        unpack8(xq, qa); unpack8(xk, ka);
        int d = g * 16 + 8 * j;
#pragma unroll
        for (int u = 0; u < 8; u++) {
            b1 += (qa[u] + EPSF) * (pks[d + u] + EPSF);
            b2 += (ka[u] + EPSF) * (pqs[d + u] + EPSF);
        }
    }
    b1 += __shfl_xor(b1, 1, 64); b1 += __shfl_xor(b1, 2, 64);
    b2 += __shfl_xor(b2, 1, 64); b2 += __shfl_xor(b2, 2, 64);
    if (g == 0) {
        float nf = (float)(l + 1);
        float cs  = (b1 + rw1_g[s * Ll + l]) * rcpf(nf);
        float csr = (b2 + rw2_g[s * Ll + l]) * rcpf(nf);
        csr = fminf(fmaxf(csr, -1.f), 1.f);
        float e = __expf(csr);
        float sal = sigf(cs);
        s2_g[s * Ll + l] = si_g[s * Ll + l] * rcpf(nf) * sal;
        e_g[s * Ll + l] = e;
        le[i] = e;
    }
    __syncthreads();
    if (t < 64) {
        float run = le[t];
#pragma unroll
        for (int off = 1; off < 64; off <<= 1) {
            float o = __shfl_up(run, off, 64);
            if (t >= off) run += o;
        }
        ecum_g[s * Ll + c * C + t] = run;
        if (t == 63) Tcs[b] = run;
    }
}

// K4: scomp + MFMA chunk KV^T[m][d] (row-copy staging from Kt/Vt).
__global__ __launch_bounds__(256) void k_kv(const unsigned short* __restrict__ Kt,
                                            const unsigned short* __restrict__ Vt,
                                            const float* __restrict__ e_g,
                                            const float* __restrict__ ecum_g,
                                            const float* __restrict__ Tcs,
                                            float* __restrict__ scomp_g,
                                            float* __restrict__ KVT) {
    __shared__ __align__(16) unsigned short skT[C * SB];   // [d][i]
    __shared__ __align__(16) unsigned short vsT[C * SB];   // [m][i] scomp-scaled
    __shared__ float lsc[C];
    __shared__ float pcsv;
    int b = blockIdx.x, s = b / NC, c = b % NC, t = threadIdx.x;
    if (t < 64) {
        float v = (t < c) ? Tcs[s * NC + t] : 0.f;
        v = waveRed(v);
        if (t == 0) pcsv = v;
    }
    __syncthreads();
    if (t < 64) {
        int l = c * C + t;
        float ls = e_g[s * Ll + l] * rcpf(pcsv + ecum_g[s * Ll + l]) * (float)(l + 1);
        lsc[t] = ls;
        scomp_g[s * Ll + l] = ls;
    }
    __syncthreads();

    size_t base = (size_t)b * 4096;
#pragma unroll
    for (int j = 0; j < 2; j++) {
        int flat = 8 * t + 2048 * j, dR = flat >> 6, i0 = flat & 63;
        *(uint4*)&skT[dR * SB + i0] = *(const uint4*)&Kt[base + flat];
        uint4 vv = *(const uint4*)&Vt[base + flat];
        float x[8];
        unpack8(vv, x);
#pragma unroll
        for (int u = 0; u < 8; u++) x[u] *= lsc[i0 + u];
        uint4 o;
        o.x = pack2(x[0], x[1]); o.y = pack2(x[2], x[3]);
        o.z = pack2(x[4], x[5]); o.w = pack2(x[6], x[7]);
        *(uint4*)&vsT[dR * SB + i0] = o;
    }
    __syncthreads();

    {   // MFMA: KVT[m][d] = sum_i vsT[m][i] * skT[d][i]
        int w = t >> 6, lane = t & 63, m = lane & 15, q = lane >> 4;
        f32x4 acc[4] = {{0,0,0,0},{0,0,0,0},{0,0,0,0},{0,0,0,0}};
#pragma unroll
        for (int kk = 0; kk < 64; kk += 32) {
            short8 a = *(const short8*)&vsT[(16 * w + m) * SB + kk + q * 8];
#pragma unroll
            for (int J = 0; J < 4; J++) {
                short8 bb = *(const short8*)&skT[(16 * J + m) * SB + kk + q * 8];
                acc[J] = MFMA16(a, bb, acc[J]);
            }
        }
#pragma unroll
        for (int J = 0; J < 4; J++)
#pragma unroll
            for (int r = 0; r < 4; r++)
                KVT[(size_t)b * 4096 + (16 * w + 4 * q + r) * 64 + 16 * J + m] = acc[J][r];
    }
}

// K5: exclusive chunk-prefix of KVT. grid=256.
__global__ __launch_bounds__(256) void k_prefixKV(float* __restrict__ KVT) {
    int bx = blockIdx.x, s = bx >> 4, sub = bx & 15;
    int e0 = sub * 256 + threadIdx.x;
    float x[NC];
#pragma unroll
    for (int cp = 0; cp < NC; cp++)
        x[cp] = KVT[(size_t)(s * NC + cp) * 4096 + e0];
    float r = 0.f;
#pragma unroll
    for (int cp = 0; cp < NC; cp++) {
        float tv = x[cp];
        KVT[(size_t)(s * NC + cp) * 4096 + e0] = r;
        r += tv;
    }
}

// K6: final — P recomputed via MFMA (no Pg); kvB overlaid on skB after P pass.
__global__ __launch_bounds__(256) void k_final(const unsigned short* __restrict__ Qb,
                                               const unsigned short* __restrict__ Kb,
                                               const unsigned short* __restrict__ Vt,
                                               const float* __restrict__ s2_g,
                                               const float* __restrict__ scomp_g,
                                               const float* __restrict__ KVT,
                                               float* __restrict__ Out) {
    __shared__ __align__(16) unsigned short sqB[C * SB];    // [i][d]
    __shared__ __align__(16) unsigned short skB[C * SB];    // sk rows; later kvB [m][d]
    __shared__ __align__(16) unsigned short vsT[C * SB];    // [m][j] raw v
    __shared__ __align__(16) unsigned short stB[C * SB];    // [i][j] masked P*scomp
    __shared__ float lsc[C], s2l[C];
    int b = blockIdx.x, s = b / NC, c = b % NC;
    int n = s / Hh, h = s % Hh, t = threadIdx.x;
    int w = t >> 6, lane = t & 63, mf = lane & 15, qq = lane >> 4;
    int I0 = 16 * w;

    if (t < 64) lsc[t] = scomp_g[s * Ll + c * C + t];
    else if (t < 128) s2l[t - 64] = s2_g[s * Ll + c * C + (t - 64)];

    // early KVT loads (hidden behind staging + P-MFMA)
    float4 kvr[4];
#pragma unroll
    for (int j = 0; j < 4; j++)
        kvr[j] = *(const float4*)&KVT[(size_t)b * 4096 + 4 * t + 1024 * j];

    size_t base = (size_t)b * 4096;
#pragma unroll
    for (int j = 0; j < 2; j++) {
        int flat = 8 * t + 2048 * j, i = flat >> 6, d0 = flat & 63;
        *(uint4*)&sqB[i * SB + d0] = *(const uint4*)&Qb[base + flat];
        *(uint4*)&skB[i * SB + d0] = *(const uint4*)&Kb[base + flat];
        *(uint4*)&vsT[i * SB + d0] = *(const uint4*)&Vt[base + flat];
    }
    __syncthreads();

    // P recompute: wave w owns row-block I0; mask+scale -> stB
    {
        f32x4 acc[4] = {{0,0,0,0},{0,0,0,0},{0,0,0,0},{0,0,0,0}};
#pragma unroll
        for (int kk = 0; kk < 64; kk += 32) {
            short8 a = *(const short8*)&sqB[(I0 + mf) * SB + kk + qq * 8];
#pragma unroll
            for (int J = 0; J < 4; J++) {
                short8 bb = *(const short8*)&skB[(16 * J + mf) * SB + kk + qq * 8];
                acc[J] = MFMA16(a, bb, acc[J]);
            }
        }
#pragma unroll
        for (int J = 0; J < 4; J++)
#pragma unroll
            for (int r = 0; r < 4; r++) {
                int i = I0 + 4 * qq + r, jj = 16 * J + mf;
                float v = (jj <= i) ? acc[J][r] * lsc[jj] : 0.f;
                stB[i * SB + jj] = f2bf(v);
            }
    }
    __syncthreads();   // skB reads done; stB ready

    // overlay kvB (= prefix KV rows [m][d]) onto skB
#pragma unroll
    for (int j = 0; j < 4; j++) {
        int flat = 4 * t + 1024 * j, i = flat >> 6, d0 = flat & 63;
        *(uint2*)&skB[i * SB + d0] = make_uint2(pack2(kvr[j].x, kvr[j].y),
                                                pack2(kvr[j].z, kvr[j].w));
    }
    __syncthreads();

    f32x4 acc[4] = {{0,0,0,0},{0,0,0,0},{0,0,0,0},{0,0,0,0}};
#pragma unroll
    for (int kk = 0; kk < 64; kk += 32) {   // mm1: sq · KVp ; mm2: stB · v
        short8 a1 = *(const short8*)&sqB[(I0 + mf) * SB + kk + qq * 8];
        short8 a2 = *(const short8*)&stB[(I0 + mf) * SB + kk + qq * 8];
#pragma unroll
        for (int J = 0; J < 4; J++) {
            short8 b1 = *(const short8*)&skB[(16 * J + mf) * SB + kk + qq * 8];
            acc[J] = MFMA16(a1, b1, acc[J]);
            short8 b2 = *(const short8*)&vsT[(16 * J + mf) * SB + kk + qq * 8];
            acc[J] = MFMA16(a2, b2, acc[J]);
        }
    }
#pragma unroll
    for (int J = 0; J < 4; J++)
#pragma unroll
        for (int r = 0; r < 4; r++) {
            int io = I0 + 4 * qq + r;
            Out[gidx(n, c * C + io, h, 16 * J + mf)] = acc[J][r] * s2l[io];
        }
}

extern "C" void kernel_launch(void* const* d_in, const int* in_sizes, int n_in,
                              void* d_out, int out_size, void* d_ws, size_t ws_size,
                              hipStream_t stream) {
    const float* Q = (const float*)d_in[0];
    const float* K = (const float*)d_in[1];
    const float* V = (const float*)d_in[2];
    float* Out = (float*)d_out;

    float* ws    = (float*)d_ws;
    float* SK    = ws;                  // SC*64
    float* SQ    = SK    + SC * 64;
    float* SKso  = SQ    + SC * 64;
    float* SQsi  = SKso  + SC * 64;
    float* si_g  = SQsi  + SC * 64;     // S*Ll each
    float* rw1_g = si_g  + S * Ll;
    float* rw2_g = rw1_g + S * Ll;
    float* s2_g  = rw2_g + S * Ll;
    float* e_g   = s2_g  + S * Ll;
    float* ecum_g= e_g   + S * Ll;
    float* scomp = ecum_g+ S * Ll;
    float* Tcs   = scomp + S * Ll;      // SC
    float* KVT   = Tcs   + SC;          // SC*4096
    unsigned short* Qb = (unsigned short*)(KVT + (size_t)SC * 4096);   // SC*4096 bf16 each
    unsigned short* Kb = Qb + (size_t)SC * 4096;
    unsigned short* Kt = Kb + (size_t)SC * 4096;
    unsigned short* Vt = Kt + (size_t)SC * 4096;

    k_stage<<<SC, 256, 0, stream>>>(Q, K, V, Qb, Kb, Kt, Vt, SK, SQ);
    k_pass1<<<SC, 256, 0, stream>>>(Qb, Kb, SK, SQ, SKso, SQsi, si_g, rw1_g, rw2_g);
    k_pass2<<<SC, 256, 0, stream>>>(Qb, Kb, SKso, SQsi, si_g, rw1_g, rw2_g, s2_g, e_g, ecum_g, Tcs);
    k_kv<<<SC, 256, 0, stream>>>(Kt, Vt, e_g, ecum_g, Tcs, scomp, KVT);
    k_prefixKV<<<256, 256, 0, stream>>>(KVT);
    k_final<<<SC, 256, 0, stream>>>(Qb, Kb, Vt, s2_g, scomp, KVT, Out);
}